// Round 2
// baseline (909.769 us; speedup 1.0000x reference)
//
#include <hip/hip_runtime.h>

typedef unsigned short u16;
typedef __attribute__((ext_vector_type(8))) short bf16x8;
typedef __attribute__((ext_vector_type(4))) float f32x4;

#define S_LEN 2048
#define DM 2048
#define KVD 512

__device__ __forceinline__ u16 f2bf(float f) {
  union { float f; unsigned int u; } v; v.f = f;
  unsigned int r = v.u + 0x7fffu + ((v.u >> 16) & 1u);
  return (u16)(r >> 16);
}

// in fp32 [K][N] -> out bf16 [N][K], 64x64 tiles
__global__ __launch_bounds__(256) void transpose_cast(const float* __restrict__ in,
                                                      u16* __restrict__ out,
                                                      int K, int N) {
  __shared__ u16 s[64][72];
  int n0 = blockIdx.x * 64, k0 = blockIdx.y * 64;
  int t = threadIdx.x;
  int r = t >> 2;            // 0..63
  int cc = (t & 3) * 16;     // 0,16,32,48
  const float* ip = in + (size_t)(k0 + r) * N + n0 + cc;
  u16 tmp[16];
#pragma unroll
  for (int i = 0; i < 16; i += 4) {
    float4 v = *(const float4*)(ip + i);
    tmp[i] = f2bf(v.x); tmp[i + 1] = f2bf(v.y);
    tmp[i + 2] = f2bf(v.z); tmp[i + 3] = f2bf(v.w);
  }
  *(uint4*)&s[r][cc] = *(uint4*)tmp;
  *(uint4*)&s[r][cc + 8] = *(uint4*)(tmp + 8);
  __syncthreads();
#pragma unroll
  for (int i = 0; i < 16; i++) tmp[i] = s[cc + i][r];
  u16* op = out + (size_t)(n0 + r) * K + k0 + cc;
  *(uint4*)op = *(uint4*)tmp;
  *(uint4*)(op + 8) = *(uint4*)(tmp + 8);
}

// C[M,N] = A[M,K] @ Bt[N,K]^T + bias[N]; 64x64 tile, BK=32, 256 thr (4 waves)
// A is fp32 (A_F32) or bf16; C is fp32 (C_F32) or bf16. Compute in bf16 MFMA.
template <bool A_F32, bool C_F32>
__global__ __launch_bounds__(256) void gemm_bt(const void* __restrict__ Av,
                                               const u16* __restrict__ Bt,
                                               const float* __restrict__ bias,
                                               void* __restrict__ Cv,
                                               int K, int N) {
  __shared__ u16 As[64][40];  // 80B rows: 16B aligned, non-pow2 bank stride
  __shared__ u16 Bs[64][40];
  int n0 = blockIdx.x * 64;
  int m0 = blockIdx.y * 64;
  int tid = threadIdx.x;
  int wave = tid >> 6, lane = tid & 63;
  int wm = (wave >> 1) * 32, wn = (wave & 1) * 32;
  int lq = lane & 15, quad = lane >> 4;
  int r = tid >> 2;        // 0..63
  int c = (tid & 3) * 8;   // 0,8,16,24

  f32x4 zero = {0.f, 0.f, 0.f, 0.f};
  f32x4 acc[2][2] = {{zero, zero}, {zero, zero}};

  const u16* Bp = Bt + (size_t)(n0 + r) * K + c;

  for (int k0 = 0; k0 < K; k0 += 32) {
    __syncthreads();
    if constexpr (A_F32) {
      const float* Ap = (const float*)Av + (size_t)(m0 + r) * K + c + k0;
      float4 a0 = *(const float4*)Ap;
      float4 a1 = *(const float4*)(Ap + 4);
      u16 t8[8] = {f2bf(a0.x), f2bf(a0.y), f2bf(a0.z), f2bf(a0.w),
                   f2bf(a1.x), f2bf(a1.y), f2bf(a1.z), f2bf(a1.w)};
      *(uint4*)&As[r][c] = *(uint4*)t8;
    } else {
      const u16* Ap = (const u16*)Av + (size_t)(m0 + r) * K + c + k0;
      *(uint4*)&As[r][c] = *(const uint4*)Ap;
    }
    *(uint4*)&Bs[r][c] = *(const uint4*)(Bp + k0);
    __syncthreads();
    bf16x8 af0 = *(const bf16x8*)&As[wm + lq][quad * 8];
    bf16x8 af1 = *(const bf16x8*)&As[wm + 16 + lq][quad * 8];
    bf16x8 bf0 = *(const bf16x8*)&Bs[wn + lq][quad * 8];
    bf16x8 bf1 = *(const bf16x8*)&Bs[wn + 16 + lq][quad * 8];
    acc[0][0] = __builtin_amdgcn_mfma_f32_16x16x32_bf16(af0, bf0, acc[0][0], 0, 0, 0);
    acc[0][1] = __builtin_amdgcn_mfma_f32_16x16x32_bf16(af0, bf1, acc[0][1], 0, 0, 0);
    acc[1][0] = __builtin_amdgcn_mfma_f32_16x16x32_bf16(af1, bf0, acc[1][0], 0, 0, 0);
    acc[1][1] = __builtin_amdgcn_mfma_f32_16x16x32_bf16(af1, bf1, acc[1][1], 0, 0, 0);
  }
#pragma unroll
  for (int i = 0; i < 2; i++)
#pragma unroll
    for (int j = 0; j < 2; j++) {
      int col = n0 + wn + j * 16 + lq;
      float bv = bias[col];
#pragma unroll
      for (int rg = 0; rg < 4; rg++) {
        int row = m0 + wm + i * 16 + quad * 4 + rg;
        float val = acc[i][j][rg] + bv;
        if constexpr (C_F32)
          ((float*)Cv)[(size_t)row * N + col] = val;
        else
          ((u16*)Cv)[(size_t)row * N + col] = f2bf(val);
      }
    }
}

// Flash attention. qh [B,S,2048] (head at (g*4+h)*64), kh/vh [B,S,512] (g*64).
// Block: one head (blockIdx.y in 0..63), 64-row Q tile (blockIdx.x in 0..31).
__global__ __launch_bounds__(256) void attn_kernel(const u16* __restrict__ qh,
                                                   const u16* __restrict__ kh,
                                                   const u16* __restrict__ vh,
                                                   u16* __restrict__ out) {
  __shared__ u16 Ks[32][72];      // [t][d]
  __shared__ u16 Vt[64][40];      // [d][t]
  __shared__ u16 Pl[4][16][40];   // per-wave P tile [s][t]

  int qt = blockIdx.x;
  int head = blockIdx.y;
  int b = head >> 5;
  int g = (head >> 2) & 7;
  int h = head & 3;
  int tid = threadIdx.x;
  int wave = tid >> 6, lane = tid & 63;
  int lq = lane & 15, quad = lane >> 4;

  const int qoff = (g * 4 + h) * 64;
  const int koff = g * 64;
  int q0 = qt * 64 + wave * 16;

  bf16x8 qf0, qf1;
  {
    const u16* qp = qh + (size_t)(b * S_LEN + q0 + lq) * DM + qoff + quad * 8;
    qf0 = *(const bf16x8*)qp;
    qf1 = *(const bf16x8*)(qp + 32);
  }

  f32x4 zero = {0.f, 0.f, 0.f, 0.f};
  f32x4 o_acc[4] = {zero, zero, zero, zero};
  float m_i[4], l_i[4];
#pragma unroll
  for (int rg = 0; rg < 4; rg++) { m_i[rg] = -3.0e38f; l_i[rg] = 0.f; }

  const float sc = 0.125f * 1.44269504089f;  // scale * log2(e)

  int sr = tid >> 3;           // 0..31
  int scol = (tid & 7) * 8;    // 0..56

  for (int t0 = 0; t0 < S_LEN; t0 += 32) {
    __syncthreads();
    {
      const u16* kp = kh + (size_t)(b * S_LEN + t0 + sr) * KVD + koff + scol;
      *(uint4*)&Ks[sr][scol] = *(const uint4*)kp;
      const u16* vp = vh + (size_t)(b * S_LEN + t0 + sr) * KVD + koff + scol;
      uint4 vv = *(const uint4*)vp;
      u16 tmp[8];
      *(uint4*)tmp = vv;
#pragma unroll
      for (int i = 0; i < 8; i++) Vt[scol + i][sr] = tmp[i];
    }
    __syncthreads();

    f32x4 s_acc[2];
#pragma unroll
    for (int nh = 0; nh < 2; nh++) {
      f32x4 a = zero;
      bf16x8 kf0 = *(const bf16x8*)&Ks[nh * 16 + lq][quad * 8];
      bf16x8 kf1 = *(const bf16x8*)&Ks[nh * 16 + lq][32 + quad * 8];
      a = __builtin_amdgcn_mfma_f32_16x16x32_bf16(qf0, kf0, a, 0, 0, 0);
      a = __builtin_amdgcn_mfma_f32_16x16x32_bf16(qf1, kf1, a, 0, 0, 0);
      s_acc[nh] = a;
    }

    float p0v[4], p1v[4];
#pragma unroll
    for (int rg = 0; rg < 4; rg++) {
      float s0 = s_acc[0][rg] * sc, s1 = s_acc[1][rg] * sc;
      float mx = fmaxf(s0, s1);
      mx = fmaxf(mx, __shfl_xor(mx, 1));
      mx = fmaxf(mx, __shfl_xor(mx, 2));
      mx = fmaxf(mx, __shfl_xor(mx, 4));
      mx = fmaxf(mx, __shfl_xor(mx, 8));
      float mnew = fmaxf(m_i[rg], mx);
      float alpha = exp2f(m_i[rg] - mnew);
      m_i[rg] = mnew;
      float p0 = exp2f(s0 - mnew);
      float p1 = exp2f(s1 - mnew);
      p0v[rg] = p0; p1v[rg] = p1;
      float ls = p0 + p1;
      ls += __shfl_xor(ls, 1);
      ls += __shfl_xor(ls, 2);
      ls += __shfl_xor(ls, 4);
      ls += __shfl_xor(ls, 8);
      l_i[rg] = l_i[rg] * alpha + ls;
      o_acc[0][rg] *= alpha;
      o_acc[1][rg] *= alpha;
      o_acc[2][rg] *= alpha;
      o_acc[3][rg] *= alpha;
    }

#pragma unroll
    for (int rg = 0; rg < 4; rg++) {
      Pl[wave][quad * 4 + rg][lq] = f2bf(p0v[rg]);
      Pl[wave][quad * 4 + rg][16 + lq] = f2bf(p1v[rg]);
    }
    __syncthreads();
    bf16x8 pf = *(const bf16x8*)&Pl[wave][lq][quad * 8];
#pragma unroll
    for (int cc = 0; cc < 4; cc++) {
      bf16x8 vf = *(const bf16x8*)&Vt[cc * 16 + lq][quad * 8];
      o_acc[cc] = __builtin_amdgcn_mfma_f32_16x16x32_bf16(pf, vf, o_acc[cc], 0, 0, 0);
    }
  }

#pragma unroll
  for (int cc = 0; cc < 4; cc++) {
#pragma unroll
    for (int rg = 0; rg < 4; rg++) {
      float val = o_acc[cc][rg] / l_i[rg];
      size_t o = (size_t)(b * S_LEN + q0 + quad * 4 + rg) * DM + qoff + cc * 16 + lq;
      out[o] = f2bf(val);
    }
  }
}

extern "C" void kernel_launch(void* const* d_in, const int* in_sizes, int n_in,
                              void* d_out, int out_size, void* d_ws, size_t ws_size,
                              hipStream_t stream) {
  const float* q  = (const float*)d_in[0];
  const float* k  = (const float*)d_in[1];
  const float* v  = (const float*)d_in[2];
  const float* Wq = (const float*)d_in[3];
  const float* bq = (const float*)d_in[4];
  const float* Wk = (const float*)d_in[5];
  const float* bk = (const float*)d_in[6];
  const float* Wv = (const float*)d_in[7];
  const float* bv = (const float*)d_in[8];
  const float* Wo = (const float*)d_in[9];
  const float* bo = (const float*)d_in[10];

  u16* p = (u16*)d_ws;
  u16* WqT = p; p += (size_t)DM * DM;
  u16* WkT = p; p += (size_t)KVD * DM;
  u16* WvT = p; p += (size_t)KVD * DM;
  u16* WoT = p; p += (size_t)DM * DM;
  u16* qhb = p; p += (size_t)2 * S_LEN * DM;
  u16* khb = p; p += (size_t)2 * S_LEN * KVD;
  u16* vhb = p; p += (size_t)2 * S_LEN * KVD;
  u16* att = p; p += (size_t)2 * S_LEN * DM;

  // weight transposes + cast: fp32 [K][N] -> bf16 [N][K]
  transpose_cast<<<dim3(DM / 64, DM / 64), 256, 0, stream>>>(Wq, WqT, DM, DM);
  transpose_cast<<<dim3(KVD / 64, DM / 64), 256, 0, stream>>>(Wk, WkT, DM, KVD);
  transpose_cast<<<dim3(KVD / 64, DM / 64), 256, 0, stream>>>(Wv, WvT, DM, KVD);
  transpose_cast<<<dim3(DM / 64, DM / 64), 256, 0, stream>>>(Wo, WoT, DM, DM);

  // projections (M = 2*2048 = 4096): A fp32, C bf16
  gemm_bt<true, false><<<dim3(DM / 64, 4096 / 64), 256, 0, stream>>>(q, WqT, bq, qhb, DM, DM);
  gemm_bt<true, false><<<dim3(KVD / 64, 4096 / 64), 256, 0, stream>>>(k, WkT, bk, khb, DM, KVD);
  gemm_bt<true, false><<<dim3(KVD / 64, 4096 / 64), 256, 0, stream>>>(v, WvT, bv, vhb, DM, KVD);

  // grouped attention: 64 heads x 32 Q-tiles
  attn_kernel<<<dim3(S_LEN / 64, 64), 256, 0, stream>>>(qhb, khb, vhb, att);

  // output projection: A bf16, C fp32
  gemm_bt<false, true><<<dim3(DM / 64, 4096 / 64), 256, 0, stream>>>(att, WoT, bo, d_out, DM, DM);
}

// Round 3
// 512.561 us; speedup vs baseline: 1.7749x; 1.7749x over previous
//
#include <hip/hip_runtime.h>

typedef unsigned short u16;
typedef unsigned int u32;
typedef __attribute__((ext_vector_type(8))) short bf16x8;
typedef __attribute__((ext_vector_type(4))) float f32x4;

#define DM 2048
#define SQ_SCALE (0.125f * 1.44269504089f)

__device__ __forceinline__ u16 f2bf(float f) {
  union { float f; u32 u; } v; v.f = f;
  u32 r = v.u + 0x7fffu + ((v.u >> 16) & 1u);
  return (u16)(r >> 16);
}
// pack two floats to (bf16(hi)<<16)|bf16(lo), round-half-up
__device__ __forceinline__ u32 pkrn(float lo, float hi) {
  union { float f; u32 u; } a, b; a.f = lo; b.f = hi;
  return ((a.u + 0x8000u) >> 16) | ((b.u + 0x8000u) & 0xffff0000u);
}
__device__ __forceinline__ void gload16(const u16* g, u16* l) {
  __builtin_amdgcn_global_load_lds((const __attribute__((address_space(1))) void*)g,
                                   (__attribute__((address_space(3))) void*)l, 16, 0, 0);
}

// fp32 [K][N] -> bf16 [N][K], 64x64 tiles (validated round 2)
__global__ __launch_bounds__(256) void transpose_cast(const float* __restrict__ in,
                                                      u16* __restrict__ out,
                                                      int K, int N) {
  __shared__ u16 s[64][72];
  int n0 = blockIdx.x * 64, k0 = blockIdx.y * 64;
  int t = threadIdx.x;
  int r = t >> 2;
  int cc = (t & 3) * 16;
  const float* ip = in + (size_t)(k0 + r) * N + n0 + cc;
  u16 tmp[16];
#pragma unroll
  for (int i = 0; i < 16; i += 4) {
    float4 v = *(const float4*)(ip + i);
    tmp[i] = f2bf(v.x); tmp[i + 1] = f2bf(v.y);
    tmp[i + 2] = f2bf(v.z); tmp[i + 3] = f2bf(v.w);
  }
  *(uint4*)&s[r][cc] = *(uint4*)tmp;
  *(uint4*)&s[r][cc + 8] = *(uint4*)(tmp + 8);
  __syncthreads();
#pragma unroll
  for (int i = 0; i < 16; i++) tmp[i] = s[cc + i][r];
  u16* op = out + (size_t)(n0 + r) * K + k0 + cc;
  *(uint4*)op = *(uint4*)tmp;
  *(uint4*)(op + 8) = *(uint4*)(tmp + 8);
}

// V^T precompute: kvb [b][s][1024] (V at col 512+g*64+d) -> vtb [b*8+g][64][2048]
__global__ __launch_bounds__(256) void transpose_v(const u16* __restrict__ kvb,
                                                   u16* __restrict__ vtb) {
  __shared__ u16 s[64][72];
  int bg = blockIdx.y;
  int t0 = blockIdx.x * 64;
  int t = threadIdx.x;
  int r = t >> 2;
  int cc = (t & 3) * 16;
  const u16* ip = kvb + ((size_t)(bg >> 3) * 2048 + t0 + r) * 1024 + 512 + (bg & 7) * 64 + cc;
  *(uint4*)&s[r][cc] = *(const uint4*)ip;
  *(uint4*)&s[r][cc + 8] = *(const uint4*)(ip + 8);
  __syncthreads();
  u16 tmp[16];
#pragma unroll
  for (int i = 0; i < 16; i++) tmp[i] = s[cc + i][r];
  u16* op = vtb + (size_t)bg * 64 * 2048 + (size_t)r * 2048 + t0 + cc;
  *(uint4*)op = *(uint4*)tmp;
  *(uint4*)(op + 8) = *(uint4*)(tmp + 8);
}

// m97-style GEMM: C[M,N] = A[M,K] @ Bt[N,K]^T + bias, 128x128 tile, BK=32.
// A2/bias2: alternate operand for n0 >= n_split (fused KV projection).
template <bool A_F32, bool C_F32>
__global__ __launch_bounds__(256) void gemm128(const void* __restrict__ Av,
                                               const void* __restrict__ Av2,
                                               const u16* __restrict__ Bt,
                                               const float* __restrict__ bias,
                                               const float* __restrict__ bias2,
                                               int n_split,
                                               void* __restrict__ Cv,
                                               int K, int N, float escale) {
  __shared__ u16 As[128 * 32];
  __shared__ u16 Bs[128 * 32];
  int n0 = blockIdx.x * 128, m0 = blockIdx.y * 128;
  const void* Ause = Av;
  const float* buse = bias;
  int boff = 0;
  if (n0 >= n_split) { Ause = Av2; buse = bias2; boff = n_split; }
  int tid = threadIdx.x, wave = tid >> 6, lane = tid & 63;
  int lq = lane & 15, quad = lane >> 4;
  int wm = (wave & 1) * 64, wn = (wave >> 1) * 64;

  f32x4 zero = {0.f, 0.f, 0.f, 0.f};
  f32x4 acc[4][4];
#pragma unroll
  for (int i = 0; i < 4; i++)
#pragma unroll
    for (int j = 0; j < 4; j++) acc[i][j] = zero;

  const u16* gB = Bt + (size_t)(n0 + wave * 16 + (lane >> 2)) * K + (lane & 3) * 8;
  u16* lB0 = &Bs[(wave * 16) * 32];
  u16* lB1 = &Bs[(64 + wave * 16) * 32];
  u16* lA0 = &As[(wave * 16) * 32];
  u16* lA1 = &As[(64 + wave * 16) * 32];
  const u16* gA = nullptr;
  const float* gAf = nullptr;
  int ar = tid >> 1, ac = (tid & 1) * 16;
  if constexpr (A_F32)
    gAf = (const float*)Ause + (size_t)(m0 + ar) * K + ac;
  else
    gA = (const u16*)Ause + (size_t)(m0 + wave * 16 + (lane >> 2)) * K + (lane & 3) * 8;

  for (int k0 = 0; k0 < K; k0 += 32) {
    if constexpr (A_F32) {
      const float* ga = gAf + k0;
      float4 f0 = *(const float4*)ga;
      float4 f1 = *(const float4*)(ga + 4);
      float4 f2 = *(const float4*)(ga + 8);
      float4 f3 = *(const float4*)(ga + 12);
      __syncthreads();
      uint4 w0 = {pkrn(f0.x, f0.y), pkrn(f0.z, f0.w), pkrn(f1.x, f1.y), pkrn(f1.z, f1.w)};
      uint4 w1 = {pkrn(f2.x, f2.y), pkrn(f2.z, f2.w), pkrn(f3.x, f3.y), pkrn(f3.z, f3.w)};
      *(uint4*)&As[ar * 32 + ac] = w0;
      *(uint4*)&As[ar * 32 + ac + 8] = w1;
      gload16(gB + k0, lB0);
      gload16(gB + (size_t)64 * K + k0, lB1);
      __syncthreads();
    } else {
      __syncthreads();
      gload16(gA + k0, lA0);
      gload16(gA + (size_t)64 * K + k0, lA1);
      gload16(gB + k0, lB0);
      gload16(gB + (size_t)64 * K + k0, lB1);
      __syncthreads();
    }
    bf16x8 af[4], bf[4];
#pragma unroll
    for (int i = 0; i < 4; i++) af[i] = *(const bf16x8*)&As[(wm + i * 16 + lq) * 32 + quad * 8];
#pragma unroll
    for (int j = 0; j < 4; j++) bf[j] = *(const bf16x8*)&Bs[(wn + j * 16 + lq) * 32 + quad * 8];
#pragma unroll
    for (int i = 0; i < 4; i++)
#pragma unroll
      for (int j = 0; j < 4; j++)
        acc[i][j] = __builtin_amdgcn_mfma_f32_16x16x32_bf16(af[i], bf[j], acc[i][j], 0, 0, 0);
  }
#pragma unroll
  for (int j = 0; j < 4; j++) {
    int col = n0 + wn + j * 16 + lq;
    float bv = buse[col - boff];
#pragma unroll
    for (int i = 0; i < 4; i++) {
#pragma unroll
      for (int rg = 0; rg < 4; rg++) {
        int row = m0 + wm + i * 16 + quad * 4 + rg;
        float val = (acc[i][j][rg] + bv) * escale;
        if constexpr (C_F32)
          ((float*)Cv)[(size_t)row * N + col] = val;
        else
          ((u16*)Cv)[(size_t)row * N + col] = f2bf(val);
      }
    }
  }
}

// Flash attention, S^T formulation, no-max softmax (Q pre-scaled by 0.125*log2e).
// Block: 256 s-rows (wave: 64), one head; T-tile 32.
// qh [b*2048+s][2048], kvb [b*2048+t][1024] (K at g*64), vtb [b*8+g][64][2048].
__global__ __launch_bounds__(256) void attn_kernel(const u16* __restrict__ qh,
                                                   const u16* __restrict__ kvb,
                                                   const u16* __restrict__ vtb,
                                                   u16* __restrict__ out) {
  __shared__ u16 Ks[32][72];
  __shared__ u16 Vt[64][40];
  int head = blockIdx.y;
  int b = head >> 5, g = (head >> 2) & 7, h = head & 3;
  int tid = threadIdx.x, wave = tid >> 6, lane = tid & 63;
  int lq = lane & 15, quad = lane >> 4;
  const int qoff = (g * 4 + h) * 64;
  const int koff = g * 64;
  int sBase = blockIdx.x * 256 + wave * 64;

  bf16x8 qf[4][2];
#pragma unroll
  for (int sb = 0; sb < 4; sb++) {
    const u16* qp = qh + (size_t)(b * 2048 + sBase + sb * 16 + lq) * DM + qoff + quad * 8;
    qf[sb][0] = *(const bf16x8*)qp;
    qf[sb][1] = *(const bf16x8*)(qp + 32);
  }

  f32x4 zero = {0.f, 0.f, 0.f, 0.f};
  f32x4 o_acc[4][4];
#pragma unroll
  for (int sb = 0; sb < 4; sb++)
#pragma unroll
    for (int cc = 0; cc < 4; cc++) o_acc[sb][cc] = zero;
  float l_acc[4] = {0.f, 0.f, 0.f, 0.f};

  int sr = tid >> 3, sc = (tid & 7) * 8;  // K staging: row t, d-chunk
  int vd = tid >> 2, vc = (tid & 3) * 8;  // V staging: row d, t-chunk
  const u16* kbase = kvb + (size_t)b * 2048 * 1024 + koff;
  const u16* vbase = vtb + (size_t)(head >> 2) * 64 * 2048 + (size_t)vd * 2048;

  int srcA = (((2 * quad) & 3) << 4) + lq;
  int srcB = (((2 * quad + 1) & 3) << 4) + lq;
  bool hi = (quad & 2) != 0;

  uint4 kreg = *(const uint4*)(kbase + (size_t)sr * 1024 + sc);
  uint4 vreg = *(const uint4*)(vbase + vc);

  for (int t0 = 0; t0 < 2048; t0 += 32) {
    __syncthreads();
    *(uint4*)&Ks[sr][sc] = kreg;
    *(uint4*)&Vt[vd][vc] = vreg;
    __syncthreads();
    int tn = (t0 + 32 < 2048) ? t0 + 32 : 0;  // prefetch next tile (dummy-safe)
    kreg = *(const uint4*)(kbase + (size_t)(tn + sr) * 1024 + sc);
    vreg = *(const uint4*)(vbase + tn + vc);

    bf16x8 kf[2][2], vf[4];
#pragma unroll
    for (int tb = 0; tb < 2; tb++) {
      kf[tb][0] = *(const bf16x8*)&Ks[tb * 16 + lq][quad * 8];
      kf[tb][1] = *(const bf16x8*)&Ks[tb * 16 + lq][32 + quad * 8];
    }
#pragma unroll
    for (int cc = 0; cc < 4; cc++) vf[cc] = *(const bf16x8*)&Vt[cc * 16 + lq][quad * 8];

#pragma unroll
    for (int sb = 0; sb < 4; sb++) {
      // S^T = K . Q^T : lane holds col s=lq, rows t = srcquad*4+rg (+16*tb)
      f32x4 st0 = __builtin_amdgcn_mfma_f32_16x16x32_bf16(kf[0][0], qf[sb][0], zero, 0, 0, 0);
      st0 = __builtin_amdgcn_mfma_f32_16x16x32_bf16(kf[0][1], qf[sb][1], st0, 0, 0, 0);
      f32x4 st1 = __builtin_amdgcn_mfma_f32_16x16x32_bf16(kf[1][0], qf[sb][0], zero, 0, 0, 0);
      st1 = __builtin_amdgcn_mfma_f32_16x16x32_bf16(kf[1][1], qf[sb][1], st1, 0, 0, 0);
      float p0[4], p1[4];
#pragma unroll
      for (int rg = 0; rg < 4; rg++) {
        p0[rg] = __builtin_amdgcn_exp2f(st0[rg]);
        p1[rg] = __builtin_amdgcn_exp2f(st1[rg]);
      }
      l_acc[sb] += ((p0[0] + p0[1]) + (p0[2] + p0[3])) + ((p1[0] + p1[1]) + (p1[2] + p1[3]));
      u32 pk00 = pkrn(p0[0], p0[1]), pk01 = pkrn(p0[2], p0[3]);
      u32 pk10 = pkrn(p1[0], p1[1]), pk11 = pkrn(p1[2], p1[3]);
      // C-layout -> A-layout via lane permute (quad Q needs t=Q*8+j)
      u32 t00 = __shfl(pk00, srcA), t10 = __shfl(pk10, srcA);
      u32 t01 = __shfl(pk01, srcA), t11 = __shfl(pk11, srcA);
      u32 t02 = __shfl(pk00, srcB), t12 = __shfl(pk10, srcB);
      u32 t03 = __shfl(pk01, srcB), t13 = __shfl(pk11, srcB);
      union { u32 u[4]; bf16x8 v; } af;
      af.u[0] = hi ? t10 : t00;
      af.u[1] = hi ? t11 : t01;
      af.u[2] = hi ? t12 : t02;
      af.u[3] = hi ? t13 : t03;
#pragma unroll
      for (int cc = 0; cc < 4; cc++)
        o_acc[sb][cc] = __builtin_amdgcn_mfma_f32_16x16x32_bf16(af.v, vf[cc], o_acc[sb][cc], 0, 0, 0);
    }
  }

#pragma unroll
  for (int sb = 0; sb < 4; sb++) {
    float lt = l_acc[sb];
    lt += __shfl_xor(lt, 16);
    lt += __shfl_xor(lt, 32);
    float inv[4];
#pragma unroll
    for (int rg = 0; rg < 4; rg++) inv[rg] = 1.0f / __shfl(lt, quad * 4 + rg);
#pragma unroll
    for (int cc = 0; cc < 4; cc++) {
#pragma unroll
      for (int rg = 0; rg < 4; rg++) {
        int row = sBase + sb * 16 + quad * 4 + rg;
        out[(size_t)(b * 2048 + row) * DM + qoff + cc * 16 + lq] = f2bf(o_acc[sb][cc][rg] * inv[rg]);
      }
    }
  }
}

extern "C" void kernel_launch(void* const* d_in, const int* in_sizes, int n_in,
                              void* d_out, int out_size, void* d_ws, size_t ws_size,
                              hipStream_t stream) {
  const float* q  = (const float*)d_in[0];
  const float* k  = (const float*)d_in[1];
  const float* v  = (const float*)d_in[2];
  const float* Wq = (const float*)d_in[3];
  const float* bq = (const float*)d_in[4];
  const float* Wk = (const float*)d_in[5];
  const float* bk = (const float*)d_in[6];
  const float* Wv = (const float*)d_in[7];
  const float* bv = (const float*)d_in[8];
  const float* Wo = (const float*)d_in[9];
  const float* bo = (const float*)d_in[10];

  u16* p = (u16*)d_ws;
  u16* WqT  = p; p += (size_t)DM * DM;        // [2048][2048]
  u16* WkvT = p; p += (size_t)1024 * DM;      // [1024][2048] (K rows 0-511, V rows 512-1023)
  u16* WoT  = p; p += (size_t)DM * DM;
  u16* qhb  = p; p += (size_t)4096 * DM;      // [4096][2048] pre-scaled Q heads
  u16* kvb  = p; p += (size_t)4096 * 1024;    // [4096][1024] K|V heads
  u16* vtb  = p; p += (size_t)16 * 64 * 2048; // [bg][64][2048] V^T
  u16* att  = p; p += (size_t)4096 * DM;

  transpose_cast<<<dim3(32, 32), 256, 0, stream>>>(Wq, WqT, DM, DM);
  transpose_cast<<<dim3(8, 32), 256, 0, stream>>>(Wk, WkvT, DM, 512);
  transpose_cast<<<dim3(8, 32), 256, 0, stream>>>(Wv, WkvT + (size_t)512 * DM, DM, 512);
  transpose_cast<<<dim3(32, 32), 256, 0, stream>>>(Wo, WoT, DM, DM);

  // Q projection (pre-scaled by 0.125*log2e), fused K|V projection
  gemm128<true, false><<<dim3(16, 32), 256, 0, stream>>>(
      q, nullptr, WqT, bq, nullptr, 1 << 30, qhb, DM, DM, SQ_SCALE);
  gemm128<true, false><<<dim3(8, 32), 256, 0, stream>>>(
      k, v, WkvT, bk, bv, 512, kvb, DM, 1024, 1.0f);

  transpose_v<<<dim3(32, 16), 256, 0, stream>>>(kvb, vtb);

  attn_kernel<<<dim3(8, 64), 256, 0, stream>>>(qhb, kvb, vtb, att);

  gemm128<false, true><<<dim3(16, 32), 256, 0, stream>>>(
      att, nullptr, WoT, bo, nullptr, 1 << 30, d_out, DM, DM, 1.0f);
}

// Round 4
// 404.971 us; speedup vs baseline: 2.2465x; 1.2657x over previous
//
#include <hip/hip_runtime.h>

typedef unsigned short u16;
typedef unsigned int u32;
typedef __attribute__((ext_vector_type(8))) short bf16x8;
typedef __attribute__((ext_vector_type(4))) float f32x4;
typedef __attribute__((ext_vector_type(16))) float f32x16;

#define DM 2048
#define SQ_SCALE (0.125f * 1.44269504089f)

__device__ __forceinline__ u16 f2bf(float f) {
  union { float f; u32 u; } v; v.f = f;
  u32 r = v.u + 0x7fffu + ((v.u >> 16) & 1u);
  return (u16)(r >> 16);
}
// pack two floats to (bf16(hi)<<16)|bf16(lo), round-half-up
__device__ __forceinline__ u32 pkrn(float lo, float hi) {
  union { float f; u32 u; } a, b; a.f = lo; b.f = hi;
  return ((a.u + 0x8000u) >> 16) | ((b.u + 0x8000u) & 0xffff0000u);
}
__device__ __forceinline__ void gload16(const u16* g, u16* l) {
  __builtin_amdgcn_global_load_lds((const __attribute__((address_space(1))) void*)g,
                                   (__attribute__((address_space(3))) void*)l, 16, 0, 0);
}

// fp32 -> bf16 elementwise, 8 elems/thread; z selects tensor
__global__ __launch_bounds__(256) void cast3(const float* __restrict__ a0,
                                             const float* __restrict__ a1,
                                             const float* __restrict__ a2,
                                             u16* __restrict__ o0,
                                             u16* __restrict__ o1,
                                             u16* __restrict__ o2) {
  const float* in; u16* out;
  if (blockIdx.z == 0) { in = a0; out = o0; }
  else if (blockIdx.z == 1) { in = a1; out = o1; }
  else { in = a2; out = o2; }
  size_t i = ((size_t)blockIdx.x * 256 + threadIdx.x) * 8;
  float4 f0 = *(const float4*)(in + i);
  float4 f1 = *(const float4*)(in + i + 4);
  uint4 w = {pkrn(f0.x, f0.y), pkrn(f0.z, f0.w), pkrn(f1.x, f1.y), pkrn(f1.z, f1.w)};
  *(uint4*)(out + i) = w;
}

// fp32 [K][N] -> bf16 [N][K], 64x64 tiles (validated round 2/3)
__global__ __launch_bounds__(256) void transpose_cast(const float* __restrict__ in,
                                                      u16* __restrict__ out,
                                                      int K, int N) {
  __shared__ u16 s[64][72];
  int n0 = blockIdx.x * 64, k0 = blockIdx.y * 64;
  int t = threadIdx.x;
  int r = t >> 2;
  int cc = (t & 3) * 16;
  const float* ip = in + (size_t)(k0 + r) * N + n0 + cc;
  u16 tmp[16];
#pragma unroll
  for (int i = 0; i < 16; i += 4) {
    float4 v = *(const float4*)(ip + i);
    tmp[i] = f2bf(v.x); tmp[i + 1] = f2bf(v.y);
    tmp[i + 2] = f2bf(v.z); tmp[i + 3] = f2bf(v.w);
  }
  *(uint4*)&s[r][cc] = *(uint4*)tmp;
  *(uint4*)&s[r][cc + 8] = *(uint4*)(tmp + 8);
  __syncthreads();
#pragma unroll
  for (int i = 0; i < 16; i++) tmp[i] = s[cc + i][r];
  u16* op = out + (size_t)(n0 + r) * K + k0 + cc;
  *(uint4*)op = *(uint4*)tmp;
  *(uint4*)(op + 8) = *(uint4*)(tmp + 8);
}

// V^T precompute: kvb [b*2048+t][1024] (V at 512+g*64+d) -> vtb [b*8+g][64][2048]
__global__ __launch_bounds__(256) void transpose_v(const u16* __restrict__ kvb,
                                                   u16* __restrict__ vtb) {
  __shared__ u16 s[64][72];
  int bg = blockIdx.y;
  int t0 = blockIdx.x * 64;
  int t = threadIdx.x;
  int r = t >> 2;
  int cc = (t & 3) * 16;
  const u16* ip = kvb + ((size_t)(bg >> 3) * 2048 + t0 + r) * 1024 + 512 + (bg & 7) * 64 + cc;
  *(uint4*)&s[r][cc] = *(const uint4*)ip;
  *(uint4*)&s[r][cc + 8] = *(const uint4*)(ip + 8);
  __syncthreads();
  u16 tmp[16];
#pragma unroll
  for (int i = 0; i < 16; i++) tmp[i] = s[cc + i][r];
  u16* op = vtb + (size_t)bg * 64 * 2048 + (size_t)r * 2048 + t0 + cc;
  *(uint4*)op = *(uint4*)tmp;
  *(uint4*)(op + 8) = *(uint4*)(tmp + 8);
}

// Fused QKV projection: C = A @ Bt^T + bias. A selected by n-tile.
// N logical 3072: [0,2048) Q -> qhb (scaled), [2048,2560) K, [2560,3072) V -> kvb.
__global__ __launch_bounds__(256) void gemm_proj(const u16* __restrict__ qb,
                                                 const u16* __restrict__ kb,
                                                 const u16* __restrict__ vb,
                                                 const u16* __restrict__ Bt,
                                                 const float* __restrict__ bqp,
                                                 const float* __restrict__ bkp,
                                                 const float* __restrict__ bvp,
                                                 u16* __restrict__ qhb,
                                                 u16* __restrict__ kvb) {
  __shared__ u16 As[128 * 32];
  __shared__ u16 Bs[128 * 32];
  int n0 = blockIdx.x * 128, m0 = blockIdx.y * 128;
  const u16* A; const float* bias; u16* C; int cw, bofs; float esc;
  if (n0 < 2048)      { A = qb; bias = bqp; C = qhb; cw = 2048; bofs = 0;    esc = SQ_SCALE; }
  else if (n0 < 2560) { A = kb; bias = bkp; C = kvb; cw = 1024; bofs = 2048; esc = 1.0f; }
  else                { A = vb; bias = bvp; C = kvb; cw = 1024; bofs = 2560; esc = 1.0f; }
  int ccol0 = (n0 < 2048) ? n0 : (n0 - 2048);

  int tid = threadIdx.x, wave = tid >> 6, lane = tid & 63;
  int lq = lane & 15, quad = lane >> 4;
  int wm = (wave & 1) * 64, wn = (wave >> 1) * 64;

  f32x4 zero = {0.f, 0.f, 0.f, 0.f};
  f32x4 acc[4][4];
#pragma unroll
  for (int i = 0; i < 4; i++)
#pragma unroll
    for (int j = 0; j < 4; j++) acc[i][j] = zero;

  const u16* gA = A + (size_t)(m0 + wave * 16 + (lane >> 2)) * 2048 + (lane & 3) * 8;
  const u16* gB = Bt + (size_t)(n0 + wave * 16 + (lane >> 2)) * 2048 + (lane & 3) * 8;
  u16* lA0 = &As[(wave * 16) * 32];
  u16* lA1 = &As[(64 + wave * 16) * 32];
  u16* lB0 = &Bs[(wave * 16) * 32];
  u16* lB1 = &Bs[(64 + wave * 16) * 32];

  for (int k0 = 0; k0 < 2048; k0 += 32) {
    __syncthreads();
    gload16(gA + k0, lA0);
    gload16(gA + (size_t)64 * 2048 + k0, lA1);
    gload16(gB + k0, lB0);
    gload16(gB + (size_t)64 * 2048 + k0, lB1);
    __syncthreads();
    bf16x8 af[4], bf[4];
#pragma unroll
    for (int i = 0; i < 4; i++) af[i] = *(const bf16x8*)&As[(wm + i * 16 + lq) * 32 + quad * 8];
#pragma unroll
    for (int j = 0; j < 4; j++) bf[j] = *(const bf16x8*)&Bs[(wn + j * 16 + lq) * 32 + quad * 8];
#pragma unroll
    for (int i = 0; i < 4; i++)
#pragma unroll
      for (int j = 0; j < 4; j++)
        acc[i][j] = __builtin_amdgcn_mfma_f32_16x16x32_bf16(af[i], bf[j], acc[i][j], 0, 0, 0);
  }
#pragma unroll
  for (int j = 0; j < 4; j++) {
    int nglob = n0 + wn + j * 16 + lq;
    float bv = bias[nglob - bofs];
    int col = ccol0 + wn + j * 16 + lq;
#pragma unroll
    for (int i = 0; i < 4; i++) {
#pragma unroll
      for (int rg = 0; rg < 4; rg++) {
        int row = m0 + wm + i * 16 + quad * 4 + rg;
        C[(size_t)row * cw + col] = f2bf((acc[i][j][rg] + bv) * esc);
      }
    }
  }
}

// O projection: fp32 C out
__global__ __launch_bounds__(256) void gemm_o(const u16* __restrict__ A,
                                              const u16* __restrict__ Bt,
                                              const float* __restrict__ bias,
                                              float* __restrict__ C) {
  __shared__ u16 As[128 * 32];
  __shared__ u16 Bs[128 * 32];
  int n0 = blockIdx.x * 128, m0 = blockIdx.y * 128;
  int tid = threadIdx.x, wave = tid >> 6, lane = tid & 63;
  int lq = lane & 15, quad = lane >> 4;
  int wm = (wave & 1) * 64, wn = (wave >> 1) * 64;

  f32x4 zero = {0.f, 0.f, 0.f, 0.f};
  f32x4 acc[4][4];
#pragma unroll
  for (int i = 0; i < 4; i++)
#pragma unroll
    for (int j = 0; j < 4; j++) acc[i][j] = zero;

  const u16* gA = A + (size_t)(m0 + wave * 16 + (lane >> 2)) * 2048 + (lane & 3) * 8;
  const u16* gB = Bt + (size_t)(n0 + wave * 16 + (lane >> 2)) * 2048 + (lane & 3) * 8;
  u16* lA0 = &As[(wave * 16) * 32];
  u16* lA1 = &As[(64 + wave * 16) * 32];
  u16* lB0 = &Bs[(wave * 16) * 32];
  u16* lB1 = &Bs[(64 + wave * 16) * 32];

  for (int k0 = 0; k0 < 2048; k0 += 32) {
    __syncthreads();
    gload16(gA + k0, lA0);
    gload16(gA + (size_t)64 * 2048 + k0, lA1);
    gload16(gB + k0, lB0);
    gload16(gB + (size_t)64 * 2048 + k0, lB1);
    __syncthreads();
    bf16x8 af[4], bf[4];
#pragma unroll
    for (int i = 0; i < 4; i++) af[i] = *(const bf16x8*)&As[(wm + i * 16 + lq) * 32 + quad * 8];
#pragma unroll
    for (int j = 0; j < 4; j++) bf[j] = *(const bf16x8*)&Bs[(wn + j * 16 + lq) * 32 + quad * 8];
#pragma unroll
    for (int i = 0; i < 4; i++)
#pragma unroll
      for (int j = 0; j < 4; j++)
        acc[i][j] = __builtin_amdgcn_mfma_f32_16x16x32_bf16(af[i], bf[j], acc[i][j], 0, 0, 0);
  }
#pragma unroll
  for (int j = 0; j < 4; j++) {
    int col = n0 + wn + j * 16 + lq;
    float bv = bias[col];
#pragma unroll
    for (int i = 0; i < 4; i++) {
#pragma unroll
      for (int rg = 0; rg < 4; rg++) {
        int row = m0 + wm + i * 16 + quad * 4 + rg;
        C[(size_t)row * 2048 + col] = acc[i][j][rg] + bv;
      }
    }
  }
}

// Flash attention v2: 32x32 MFMA, S^T = K.Q^T, PV full-rate via xor-32 exchange.
// Block: 256 s-rows (64/wave), one head. T-tile 32.
__global__ __launch_bounds__(256) void attn2(const u16* __restrict__ qh,
                                             const u16* __restrict__ kvb,
                                             const u16* __restrict__ vtb,
                                             u16* __restrict__ out) {
  __shared__ u16 Ks[32][72];   // [t][d] 144B rows
  __shared__ u16 Vs[64][40];   // [d][t] 80B rows
  __shared__ float Ls[4][2][32];
  int head = blockIdx.y;
  int b = head >> 5, g = (head >> 2) & 7, h = head & 3;
  int tid = threadIdx.x, wave = tid >> 6, lane = tid & 63;
  int lh = lane & 31, hi = lane >> 5;
  const int qoff = (g * 4 + h) * 64;
  const int koff = g * 64;
  int sBase = blockIdx.x * 256 + wave * 64;

  // Q as B-operand (Q^T): lane n=s=lh, k=d = st*16 + hi*8 + j
  bf16x8 qf[2][4];
#pragma unroll
  for (int sb = 0; sb < 2; sb++)
#pragma unroll
    for (int st = 0; st < 4; st++)
      qf[sb][st] = *(const bf16x8*)(qh + (size_t)(b * 2048 + sBase + sb * 32 + lh) * DM +
                                    qoff + st * 16 + hi * 8);

  f32x16 o_acc[2][2];
#pragma unroll
  for (int sb = 0; sb < 2; sb++)
#pragma unroll
    for (int db = 0; db < 2; db++)
#pragma unroll
      for (int r = 0; r < 16; r++) o_acc[sb][db][r] = 0.f;
  float l_acc[2] = {0.f, 0.f};

  int sr = tid >> 3, sc = (tid & 7) * 8;  // K staging
  int vd = tid >> 2, vc = (tid & 3) * 8;  // V^T staging
  const u16* kbase = kvb + (size_t)b * 2048 * 1024 + koff;
  const u16* vbase = vtb + (size_t)(head >> 2) * 64 * 2048 + (size_t)vd * 2048;

  uint4 kreg = *(const uint4*)(kbase + (size_t)sr * 1024 + sc);
  uint4 vreg = *(const uint4*)(vbase + vc);

  for (int t0 = 0; t0 < 2048; t0 += 32) {
    __syncthreads();
    *(uint4*)&Ks[sr][sc] = kreg;
    *(uint4*)&Vs[vd][vc] = vreg;
    __syncthreads();
    int tn = (t0 + 32 < 2048) ? t0 + 32 : 0;
    kreg = *(const uint4*)(kbase + (size_t)(tn + sr) * 1024 + sc);
    vreg = *(const uint4*)(vbase + tn + vc);

    bf16x8 kf[4], vf[2][2];
#pragma unroll
    for (int st = 0; st < 4; st++) kf[st] = *(const bf16x8*)&Ks[lh][st * 16 + hi * 8];
#pragma unroll
    for (int T = 0; T < 2; T++)
#pragma unroll
      for (int db = 0; db < 2; db++)
        vf[T][db] = *(const bf16x8*)&Vs[db * 32 + lh][T * 16 + hi * 8];

#pragma unroll
    for (int sb = 0; sb < 2; sb++) {
      f32x16 st_acc;
#pragma unroll
      for (int r = 0; r < 16; r++) st_acc[r] = 0.f;
#pragma unroll
      for (int st = 0; st < 4; st++)
        st_acc = __builtin_amdgcn_mfma_f32_32x32x16_bf16(kf[st], qf[sb][st], st_acc, 0, 0, 0);
      // S^T: lane holds col s=lh, rows t=(r&3)+8*(r>>2)+4*hi
      float pr[16];
#pragma unroll
      for (int r = 0; r < 16; r++) pr[r] = __builtin_amdgcn_exp2f(st_acc[r]);
      float s0 = ((pr[0] + pr[1]) + (pr[2] + pr[3])) + ((pr[4] + pr[5]) + (pr[6] + pr[7]));
      float s1 = ((pr[8] + pr[9]) + (pr[10] + pr[11])) + ((pr[12] + pr[13]) + (pr[14] + pr[15]));
      l_acc[sb] += s0 + s1;
      u32 pk[8];
#pragma unroll
      for (int a = 0; a < 4; a++) {
        pk[2 * a] = pkrn(pr[4 * a], pr[4 * a + 1]);
        pk[2 * a + 1] = pkrn(pr[4 * a + 2], pr[4 * a + 3]);
      }
#pragma unroll
      for (int T = 0; T < 2; T++) {
        // A-operand for PV needs t = 16T + 8*hi + j; exchange halves via xor-32
        u32 E0 = hi ? pk[4 * T] : pk[4 * T + 2];
        u32 E1 = hi ? pk[4 * T + 1] : pk[4 * T + 3];
        u32 X0 = __shfl_xor(E0, 32);
        u32 X1 = __shfl_xor(E1, 32);
        union { u32 u[4]; bf16x8 v; } af;
        af.u[0] = hi ? X0 : pk[4 * T];
        af.u[1] = hi ? X1 : pk[4 * T + 1];
        af.u[2] = hi ? pk[4 * T + 2] : X0;
        af.u[3] = hi ? pk[4 * T + 3] : X1;
#pragma unroll
        for (int db = 0; db < 2; db++)
          o_acc[sb][db] = __builtin_amdgcn_mfma_f32_32x32x16_bf16(af.v, vf[T][db], o_acc[sb][db], 0, 0, 0);
      }
    }
  }

  // epilogue: l broadcast via LDS, normalize, store
#pragma unroll
  for (int sb = 0; sb < 2; sb++) {
    float lt = l_acc[sb] + __shfl_xor(l_acc[sb], 32);
    Ls[wave][sb][lh] = 1.0f / lt;
  }
  __builtin_amdgcn_wave_barrier();
#pragma unroll
  for (int sb = 0; sb < 2; sb++) {
    f32x4 inv[4];
#pragma unroll
    for (int a = 0; a < 4; a++) inv[a] = *(const f32x4*)&Ls[wave][sb][8 * a + 4 * hi];
#pragma unroll
    for (int db = 0; db < 2; db++) {
#pragma unroll
      for (int r = 0; r < 16; r++) {
        int srow = (r & 3) + 8 * (r >> 2) + 4 * hi;
        size_t o = (size_t)(b * 2048 + sBase + sb * 32 + srow) * DM + qoff + db * 32 + lh;
        out[o] = f2bf(o_acc[sb][db][r] * inv[r >> 2][r & 3]);
      }
    }
  }
}

extern "C" void kernel_launch(void* const* d_in, const int* in_sizes, int n_in,
                              void* d_out, int out_size, void* d_ws, size_t ws_size,
                              hipStream_t stream) {
  const float* q  = (const float*)d_in[0];
  const float* k  = (const float*)d_in[1];
  const float* v  = (const float*)d_in[2];
  const float* Wq = (const float*)d_in[3];
  const float* bq = (const float*)d_in[4];
  const float* Wk = (const float*)d_in[5];
  const float* bk = (const float*)d_in[6];
  const float* Wv = (const float*)d_in[7];
  const float* bv = (const float*)d_in[8];
  const float* Wo = (const float*)d_in[9];
  const float* bo = (const float*)d_in[10];

  u16* p = (u16*)d_ws;
  u16* WqkvT = p; p += (size_t)3072 * 2048;   // rows: 0-2047 Wq^T, 2048-2559 Wk^T, 2560-3071 Wv^T
  u16* WoT   = p; p += (size_t)2048 * 2048;
  u16* qb    = p; p += (size_t)4096 * 2048;   // bf16 casts of q/k/v; att aliases qb
  u16* kb    = p; p += (size_t)4096 * 2048;
  u16* vb    = p; p += (size_t)4096 * 2048;
  u16* qhb   = p; p += (size_t)4096 * 2048;
  u16* kvb   = p; p += (size_t)4096 * 1024;
  u16* vtb   = p; p += (size_t)16 * 64 * 2048;
  u16* att   = qb;  // reuse: qb dead after gemm_proj

  cast3<<<dim3(4096, 1, 3), 256, 0, stream>>>(q, k, v, qb, kb, vb);

  transpose_cast<<<dim3(32, 32), 256, 0, stream>>>(Wq, WqkvT, 2048, 2048);
  transpose_cast<<<dim3(8, 32), 256, 0, stream>>>(Wk, WqkvT + (size_t)2048 * 2048, 2048, 512);
  transpose_cast<<<dim3(8, 32), 256, 0, stream>>>(Wv, WqkvT + (size_t)2560 * 2048, 2048, 512);
  transpose_cast<<<dim3(32, 32), 256, 0, stream>>>(Wo, WoT, 2048, 2048);

  gemm_proj<<<dim3(24, 32), 256, 0, stream>>>(qb, kb, vb, WqkvT, bq, bk, bv, qhb, kvb);

  transpose_v<<<dim3(32, 16), 256, 0, stream>>>(kvb, vtb);

  attn2<<<dim3(8, 64), 256, 0, stream>>>(qhb, kvb, vtb, att);

  gemm_o<<<dim3(16, 32), 256, 0, stream>>>(att, WoT, bo, (float*)d_out);
}